// Round 6
// baseline (463.106 us; speedup 1.0000x reference)
//
#include <hip/hip_runtime.h>
#include <hip/hip_bf16.h>

#define N_NODES   100000
#define N_EDGES   1600000
#define F_IN      64
#define HID       64
#define N_CLASSES 45
#define N_GRAPHS  256
#define SB        98          // super-buckets: bucket = dst >> 10 (0..97)
#define CAP       17920       // fixed bucket capacity (mean 16327, sigma 127 -> +12 sigma)
#define CHUNK     8192        // edges per scatter workgroup
#define NCHUNK    196         // ceil(N_EDGES / CHUNK)

__device__ __forceinline__ float rl_f(float v, int k) {
    return __uint_as_float(__builtin_amdgcn_readlane(__float_as_uint(v), k));
}
__device__ __forceinline__ int rl_i(int v, int k) {
    return __builtin_amdgcn_readlane(v, k);
}

// ---------------- CSR build: bucket counting sort ----------------

// multisplit: stage 8192 edges in LDS by bucket, flush contiguous runs into
// fixed-capacity bucket regions (binned[b*CAP ...]). payload: src | dstLow<<17
// dst values stashed in LDS during the histogram pass (read dst once).
__global__ __launch_bounds__(256) void k_scatter(const int* __restrict__ src, const int* __restrict__ dst,
                                                 int* __restrict__ bcur, int* __restrict__ binned) {
    __shared__ int stg[CHUNK];
    __shared__ int dbuf[CHUNK];
    __shared__ int h[SB], lbase[SB], gbase[SB], cur[SB];
    __shared__ int ss[128];
    int t = threadIdx.x;
    if (t < SB) h[t] = 0;
    __syncthreads();
    int base4 = blockIdx.x * (CHUNK / 4);
    // phase 1: load dst -> LDS stash + local histogram
    #pragma unroll
    for (int i = 0; i < CHUNK / 1024; i++) {
        int l4 = i * 256 + t;
        int e4 = base4 + l4;
        if (e4 < N_EDGES / 4) {
            int4 d = ((const int4*)dst)[e4];
            ((int4*)dbuf)[l4] = d;
            atomicAdd(&h[d.x >> 10], 1);
            atomicAdd(&h[d.y >> 10], 1);
            atomicAdd(&h[d.z >> 10], 1);
            atomicAdd(&h[d.w >> 10], 1);
        }
    }
    __syncthreads();
    // phase 2: local exclusive scan + global space reservation per bucket
    if (t < 128) ss[t] = (t < SB) ? h[t] : 0;
    __syncthreads();
    for (int o = 1; o < 128; o <<= 1) {
        int x = 0;
        if (t < 128 && t >= o) x = ss[t - o];
        __syncthreads();
        if (t < 128 && t >= o) ss[t] += x;
        __syncthreads();
    }
    if (t < SB) {
        int ex = ss[t] - h[t];
        lbase[t] = ex;
        cur[t]   = ex;
        gbase[t] = t * CAP + atomicAdd(&bcur[t], h[t]);
    }
    __syncthreads();
    // phase 3: read src (dst from LDS), scatter packed payload into LDS staging
    #pragma unroll
    for (int i = 0; i < CHUNK / 1024; i++) {
        int l4 = i * 256 + t;
        int e4 = base4 + l4;
        if (e4 < N_EDGES / 4) {
            int4 s4 = ((const int4*)src)[e4];
            int4 d  = ((int4*)dbuf)[l4];
            int q;
            q = atomicAdd(&cur[d.x >> 10], 1); stg[q] = s4.x | ((d.x & 1023) << 17);
            q = atomicAdd(&cur[d.y >> 10], 1); stg[q] = s4.y | ((d.y & 1023) << 17);
            q = atomicAdd(&cur[d.z >> 10], 1); stg[q] = s4.z | ((d.z & 1023) << 17);
            q = atomicAdd(&cur[d.w >> 10], 1); stg[q] = s4.w | ((d.w & 1023) << 17);
        }
    }
    __syncthreads();
    // phase 4: flush each bucket's run contiguously (wave per bucket, round-robin)
    int wv = t >> 6, lane = t & 63;
    for (int b = wv; b < SB; b += 4) {
        int n = h[b], lb = lbase[b], gb = gbase[b];
        for (int i = lane; i < n; i += 64)
            binned[gb + i] = stg[lb + i];
    }
}

// per-bucket: degrees -> dinv/dinv2 + per-node csr ranges + fill csr (src only)
__global__ __launch_bounds__(256) void k_bcsr(const int* __restrict__ binned, const int* __restrict__ bcur,
                                              int2* __restrict__ range, float* __restrict__ dinv,
                                              float* __restrict__ dinv2, int* __restrict__ csr) {
    __shared__ int h[1024];
    __shared__ int ts[256];
    int t = threadIdx.x;
    int b = blockIdx.x;
    int nb0  = b << 10;
    int ebeg = b * CAP;
    int ecnt = bcur[b]; if (ecnt > CAP) ecnt = CAP;
    #pragma unroll
    for (int i = 0; i < 4; i++) h[t + i * 256] = 0;
    __syncthreads();
    for (int i = t; i < ecnt; i += 256)
        atomicAdd(&h[binned[ebeg + i] >> 17], 1);
    __syncthreads();
    int c0 = h[t * 4], c1 = h[t * 4 + 1], c2 = h[t * 4 + 2], c3 = h[t * 4 + 3];
    int tot = c0 + c1 + c2 + c3;
    ts[t] = tot;
    __syncthreads();
    for (int o = 1; o < 256; o <<= 1) {
        int x = (t >= o) ? ts[t - o] : 0;
        __syncthreads();
        if (t >= o) ts[t] += x;
        __syncthreads();
    }
    int ex = ts[t] - tot + ebeg;
    int n0 = nb0 + t * 4;
    int e0 = ex, e1 = ex + c0, e2 = e1 + c1, e3 = e2 + c2;
    if (n0 < N_NODES) {                  // bucket node-range is 4-aligned
        int eb[4] = { e0, e1, e2, e3 };
        int cc[4] = { c0, c1, c2, c3 };
        #pragma unroll
        for (int i = 0; i < 4; i++) {
            range[n0 + i] = make_int2(eb[i], eb[i] + cc[i]);
            float inv = 1.0f / (float)(cc[i] + 1);   // +1 self loop
            dinv2[n0 + i] = inv;
            dinv[n0 + i]  = sqrtf(inv);
        }
    }
    __syncthreads();
    // repurpose h[] as per-node write cursors
    h[t * 4] = e0; h[t * 4 + 1] = e1; h[t * 4 + 2] = e2; h[t * 4 + 3] = e3;
    __syncthreads();
    for (int i = t; i < ecnt; i += 256) {
        int p    = binned[ebeg + i];
        int dlow = p >> 17;
        int q = atomicAdd(&h[dlow], 1);
        csr[q] = p & 0x1FFFF;
    }
}

// ---------------- GEMM: H1 = x @ W1 (layer-1 input only) ----------------
__global__ __launch_bounds__(256, 4) void k_gemm(const float* __restrict__ in,
                                                 const float* __restrict__ W,
                                                 float* __restrict__ Hout) {
    int lane = threadIdx.x & 63;
    int wv   = threadIdx.x >> 6;
    float Wreg[64];
    #pragma unroll
    for (int k = 0; k < 64; k++) Wreg[k] = W[k * 64 + lane];

    int base = blockIdx.x * 32 + wv * 8;
    #pragma unroll 2
    for (int r = 0; r < 8; r++) {
        int row = base + r;                       // grid exact, no guard
        float xv = in[(size_t)row * 64 + lane];
        float acc = 0.f;
        #pragma unroll
        for (int k = 0; k < 64; k++)
            acc = fmaf(rl_f(xv, k), Wreg[k], acc);
        Hout[(size_t)row * 64 + lane] = acc;
    }
}

// ---------------- Aggregation (gather), optionally fused with next GEMM ----
// A[n] = b + H[n]*dinv2[n] + dinv[n] * sum_j dinv[src_j] * H[src_j]
// FUSE: Out[n] = relu(A[n]) @ Wn   (the wave holds the whole A row, one elem
//        per lane -> readlane-broadcast GEMV, W column preloaded in VGPRs)
// else: Out[n] = A[n]
template<bool FUSE>
__global__ __launch_bounds__(256, FUSE ? 4 : 8) void k_agg(const float* __restrict__ Hbuf,
                                                           const int2* __restrict__ range,
                                                           const int* __restrict__ csr,
                                                           const float* __restrict__ dinv,
                                                           const float* __restrict__ dinv2,
                                                           const float* __restrict__ bias,
                                                           const float* __restrict__ Wn,
                                                           float* __restrict__ Out) {
    int wv   = threadIdx.x >> 6;
    int lane = threadIdx.x & 63;
    int node = blockIdx.x * 4 + wv;               // grid exact (25000*4)

    float Wreg[FUSE ? 64 : 1];
    if (FUSE) {
        #pragma unroll
        for (int k = 0; k < 64; k++) Wreg[k] = Wn[k * 64 + lane];
    }

    int2 r = range[node];
    int beg = r.x, end = r.y;
    float hself = Hbuf[(size_t)node * 64 + lane];
    float a0 = 0.f, a1 = 0.f, a2 = 0.f, a3 = 0.f;

    for (int cb = beg; cb < end; cb += 64) {
        int rem = end - cb; if (rem > 64) rem = 64;
        int ci = 0;
        if (lane < rem) ci = csr[cb + lane];
        float cs = dinv[ci];                      // per-lane 4B gather, L2-hot table
        int j = 0;
        for (; j + 8 <= rem; j += 8) {
            int   s0 = rl_i(ci, j),     s1 = rl_i(ci, j + 1);
            int   s2 = rl_i(ci, j + 2), s3 = rl_i(ci, j + 3);
            int   s4 = rl_i(ci, j + 4), s5 = rl_i(ci, j + 5);
            int   s6 = rl_i(ci, j + 6), s7 = rl_i(ci, j + 7);
            float c0 = rl_f(cs, j),     c1 = rl_f(cs, j + 1);
            float c2 = rl_f(cs, j + 2), c3 = rl_f(cs, j + 3);
            float c4 = rl_f(cs, j + 4), c5 = rl_f(cs, j + 5);
            float c6 = rl_f(cs, j + 6), c7 = rl_f(cs, j + 7);
            float h0 = Hbuf[(size_t)s0 * 64 + lane];
            float h1 = Hbuf[(size_t)s1 * 64 + lane];
            float h2 = Hbuf[(size_t)s2 * 64 + lane];
            float h3 = Hbuf[(size_t)s3 * 64 + lane];
            float h4 = Hbuf[(size_t)s4 * 64 + lane];
            float h5 = Hbuf[(size_t)s5 * 64 + lane];
            float h6 = Hbuf[(size_t)s6 * 64 + lane];
            float h7 = Hbuf[(size_t)s7 * 64 + lane];
            a0 = fmaf(h0, c0, a0);
            a1 = fmaf(h1, c1, a1);
            a2 = fmaf(h2, c2, a2);
            a3 = fmaf(h3, c3, a3);
            a0 = fmaf(h4, c4, a0);
            a1 = fmaf(h5, c5, a1);
            a2 = fmaf(h6, c6, a2);
            a3 = fmaf(h7, c7, a3);
        }
        for (; j + 2 <= rem; j += 2) {
            int   s0 = rl_i(ci, j),     s1 = rl_i(ci, j + 1);
            float c0 = rl_f(cs, j),     c1 = rl_f(cs, j + 1);
            float h0 = Hbuf[(size_t)s0 * 64 + lane];
            float h1 = Hbuf[(size_t)s1 * 64 + lane];
            a0 = fmaf(h0, c0, a0);
            a1 = fmaf(h1, c1, a1);
        }
        if (j < rem) {
            int   s0 = rl_i(ci, j);
            float c0 = rl_f(cs, j);
            a0 = fmaf(Hbuf[(size_t)s0 * 64 + lane], c0, a0);
        }
    }
    float esum = (a0 + a1) + (a2 + a3);
    float A = fmaf(dinv[node], esum, fmaf(hself, dinv2[node], bias[lane]));
    if (FUSE) {
        float rv = fmaxf(A, 0.f);                 // relu; wave holds full A row
        float o = 0.f;
        #pragma unroll
        for (int k = 0; k < 64; k++)
            o = fmaf(rl_f(rv, k), Wreg[k], o);
        Out[(size_t)node * 64 + lane] = o;        // = H_next[n][lane]
    } else {
        Out[(size_t)node * 64 + lane] = A;
    }
}

// ---------------- Pooling + classifier ----------------
__device__ __forceinline__ int lbound(const int* __restrict__ a, int n, int v) {
    int lo = 0, hi = n;
    while (lo < hi) { int m = (lo + hi) >> 1; if (a[m] < v) lo = m + 1; else hi = m; }
    return lo;
}

__global__ __launch_bounds__(1024) void k_pool(const float* __restrict__ A, const int* __restrict__ batch,
                                               const float* __restrict__ Wl, const float* __restrict__ bl,
                                               float* __restrict__ out) {
    __shared__ float red[16][64];
    __shared__ int bounds[2];
    int g    = blockIdx.x;
    int t    = threadIdx.x;
    int wv   = t >> 6;
    int lane = t & 63;
    if (t == 0) bounds[0] = lbound(batch, N_NODES, g);
    if (t == 1) bounds[1] = lbound(batch, N_NODES, g + 1);
    __syncthreads();
    int beg = bounds[0], end = bounds[1];

    float a0 = 0.f, a1 = 0.f;
    int i = beg + wv;
    for (; i + 16 < end; i += 32) {
        a0 += A[(size_t)i * 64 + lane];
        a1 += A[(size_t)(i + 16) * 64 + lane];
    }
    if (i < end) a0 += A[(size_t)i * 64 + lane];
    red[wv][lane] = a0 + a1;
    __syncthreads();
    if (wv == 0) {
        float s = 0.f;
        #pragma unroll
        for (int w = 0; w < 16; w++) s += red[w][lane];
        float cntf = (float)(end - beg);
        red[0][lane] = s / fmaxf(cntf, 1.0f);
    }
    __syncthreads();
    if (t < N_CLASSES) {
        float o = bl[t];
        #pragma unroll
        for (int k = 0; k < HID; k++) o = fmaf(red[0][k], Wl[k * N_CLASSES + t], o);
        out[g * N_CLASSES + t] = o;
    }
}

// ---------------- launch ----------------

extern "C" void kernel_launch(void* const* d_in, const int* in_sizes, int n_in,
                              void* d_out, int out_size, void* d_ws, size_t ws_size,
                              hipStream_t stream) {
    const float* x     = (const float*)d_in[0];
    const int*   eidx  = (const int*)  d_in[1];
    const int*   batch = (const int*)  d_in[2];
    const float* W1 = (const float*)d_in[3];
    const float* b1 = (const float*)d_in[4];
    const float* W2 = (const float*)d_in[5];
    const float* b2 = (const float*)d_in[6];
    const float* W3 = (const float*)d_in[7];
    const float* b3 = (const float*)d_in[8];
    const float* Wl = (const float*)d_in[9];
    const float* bl = (const float*)d_in[10];
    const int* src = eidx;
    const int* dst = eidx + N_EDGES;

    char* p = (char*)d_ws;
    auto alloc = [&](size_t bytes) -> void* {
        void* r = (void*)p;
        p += (bytes + 255) & ~(size_t)255;
        return r;
    };
    int2*  range = (int2*) alloc((size_t)N_NODES * 8);
    float* dinv  = (float*)alloc((size_t)N_NODES * 4);
    float* dinv2 = (float*)alloc((size_t)N_NODES * 4);
    int*   csr   = (int*)  alloc((size_t)SB * CAP * 4);
    float* Hb    = (float*)alloc((size_t)N_NODES * 64 * 4);
    float* Bb    = (float*)alloc((size_t)N_NODES * 64 * 4);
    int*   bcur  = (int*)  alloc((size_t)SB * 4);
    int*   binned = (int*)Hb;   // 7.0 MB scratch aliased onto Hb (dead after k_bcsr)

    const int gemm_grid = N_NODES / 32;            // 3125, exact
    const int agg_grid  = N_NODES / 4;             // 25000, exact

    // ---- CSR build ----
    hipMemsetAsync(bcur, 0, (size_t)SB * 4, stream);
    k_scatter<<<NCHUNK, 256, 0, stream>>>(src, dst, bcur, binned);
    k_bcsr   <<<SB, 256, 0, stream>>>(binned, bcur, range, dinv, dinv2, csr);

    // layer 1 GEMM: x -> H1
    k_gemm<<<gemm_grid, 256, 0, stream>>>(x, W1, Hb);
    // agg1 + fused relu+W2: H1 -> H2
    k_agg<true ><<<agg_grid, 256, 0, stream>>>(Hb, range, csr, dinv, dinv2, b1, W2, Bb);
    // agg2 + fused relu+W3: H2 -> H3
    k_agg<true ><<<agg_grid, 256, 0, stream>>>(Bb, range, csr, dinv, dinv2, b2, W3, Hb);
    // agg3 (plain): H3 -> A3
    k_agg<false><<<agg_grid, 256, 0, stream>>>(Hb, range, csr, dinv, dinv2, b3, nullptr, Bb);

    // pooling + classifier
    k_pool<<<N_GRAPHS, 1024, 0, stream>>>(Bb, batch, Wl, bl, (float*)d_out);
}

// Round 7
// 452.860 us; speedup vs baseline: 1.0226x; 1.0226x over previous
//
#include <hip/hip_runtime.h>
#include <hip/hip_bf16.h>

#define N_NODES   100000
#define N_EDGES   1600000
#define F_IN      64
#define HID       64
#define N_CLASSES 45
#define N_GRAPHS  256
#define SB        98          // super-buckets: bucket = dst >> 10 (0..97)
#define CAP       17920       // fixed bucket capacity (mean 16327, sigma 127 -> +12 sigma)
#define CHUNK     8192        // edges per scatter workgroup
#define NCHUNK    196         // ceil(N_EDGES / CHUNK)

__device__ __forceinline__ float rl_f(float v, int k) {
    return __uint_as_float(__builtin_amdgcn_readlane(__float_as_uint(v), k));
}
__device__ __forceinline__ int rl_i(int v, int k) {
    return __builtin_amdgcn_readlane(v, k);
}

// ---------------- CSR build: bucket counting sort ----------------

__global__ __launch_bounds__(256) void k_scatter(const int* __restrict__ src, const int* __restrict__ dst,
                                                 int* __restrict__ bcur, int* __restrict__ binned) {
    __shared__ int stg[CHUNK];
    __shared__ int dbuf[CHUNK];
    __shared__ int h[SB], lbase[SB], gbase[SB], cur[SB];
    __shared__ int ss[128];
    int t = threadIdx.x;
    if (t < SB) h[t] = 0;
    __syncthreads();
    int base4 = blockIdx.x * (CHUNK / 4);
    #pragma unroll
    for (int i = 0; i < CHUNK / 1024; i++) {
        int l4 = i * 256 + t;
        int e4 = base4 + l4;
        if (e4 < N_EDGES / 4) {
            int4 d = ((const int4*)dst)[e4];
            ((int4*)dbuf)[l4] = d;
            atomicAdd(&h[d.x >> 10], 1);
            atomicAdd(&h[d.y >> 10], 1);
            atomicAdd(&h[d.z >> 10], 1);
            atomicAdd(&h[d.w >> 10], 1);
        }
    }
    __syncthreads();
    if (t < 128) ss[t] = (t < SB) ? h[t] : 0;
    __syncthreads();
    for (int o = 1; o < 128; o <<= 1) {
        int x = 0;
        if (t < 128 && t >= o) x = ss[t - o];
        __syncthreads();
        if (t < 128 && t >= o) ss[t] += x;
        __syncthreads();
    }
    if (t < SB) {
        int ex = ss[t] - h[t];
        lbase[t] = ex;
        cur[t]   = ex;
        gbase[t] = t * CAP + atomicAdd(&bcur[t], h[t]);
    }
    __syncthreads();
    #pragma unroll
    for (int i = 0; i < CHUNK / 1024; i++) {
        int l4 = i * 256 + t;
        int e4 = base4 + l4;
        if (e4 < N_EDGES / 4) {
            int4 s4 = ((const int4*)src)[e4];
            int4 d  = ((int4*)dbuf)[l4];
            int q;
            q = atomicAdd(&cur[d.x >> 10], 1); stg[q] = s4.x | ((d.x & 1023) << 17);
            q = atomicAdd(&cur[d.y >> 10], 1); stg[q] = s4.y | ((d.y & 1023) << 17);
            q = atomicAdd(&cur[d.z >> 10], 1); stg[q] = s4.z | ((d.z & 1023) << 17);
            q = atomicAdd(&cur[d.w >> 10], 1); stg[q] = s4.w | ((d.w & 1023) << 17);
        }
    }
    __syncthreads();
    int wv = t >> 6, lane = t & 63;
    for (int b = wv; b < SB; b += 4) {
        int n = h[b], lb = lbase[b], gb = gbase[b];
        for (int i = lane; i < n; i += 64)
            binned[gb + i] = stg[lb + i];
    }
}

__global__ __launch_bounds__(256) void k_bcsr(const int* __restrict__ binned, const int* __restrict__ bcur,
                                              int2* __restrict__ range, float* __restrict__ dinv,
                                              float* __restrict__ dinv2, int* __restrict__ csr) {
    __shared__ int h[1024];
    __shared__ int ts[256];
    int t = threadIdx.x;
    int b = blockIdx.x;
    int nb0  = b << 10;
    int ebeg = b * CAP;
    int ecnt = bcur[b]; if (ecnt > CAP) ecnt = CAP;
    #pragma unroll
    for (int i = 0; i < 4; i++) h[t + i * 256] = 0;
    __syncthreads();
    for (int i = t; i < ecnt; i += 256)
        atomicAdd(&h[binned[ebeg + i] >> 17], 1);
    __syncthreads();
    int c0 = h[t * 4], c1 = h[t * 4 + 1], c2 = h[t * 4 + 2], c3 = h[t * 4 + 3];
    int tot = c0 + c1 + c2 + c3;
    ts[t] = tot;
    __syncthreads();
    for (int o = 1; o < 256; o <<= 1) {
        int x = (t >= o) ? ts[t - o] : 0;
        __syncthreads();
        if (t >= o) ts[t] += x;
        __syncthreads();
    }
    int ex = ts[t] - tot + ebeg;
    int n0 = nb0 + t * 4;
    int e0 = ex, e1 = ex + c0, e2 = e1 + c1, e3 = e2 + c2;
    if (n0 < N_NODES) {
        int eb[4] = { e0, e1, e2, e3 };
        int cc[4] = { c0, c1, c2, c3 };
        #pragma unroll
        for (int i = 0; i < 4; i++) {
            range[n0 + i] = make_int2(eb[i], eb[i] + cc[i]);
            float inv = 1.0f / (float)(cc[i] + 1);   // +1 self loop
            dinv2[n0 + i] = inv;
            dinv[n0 + i]  = sqrtf(inv);
        }
    }
    __syncthreads();
    h[t * 4] = e0; h[t * 4 + 1] = e1; h[t * 4 + 2] = e2; h[t * 4 + 3] = e3;
    __syncthreads();
    for (int i = t; i < ecnt; i += 256) {
        int p    = binned[ebeg + i];
        int dlow = p >> 17;
        int q = atomicAdd(&h[dlow], 1);
        csr[q] = p & 0x1FFFF;
    }
}

// ---------------- GEMM: H1 = x @ W1 ----------------
// 8 rows/wave; W streamed in 8-row groups (L1-hot), no Wreg[64] preload,
// no occupancy cap. 8 independent FMA chains per k.
__global__ __launch_bounds__(256) void k_gemm(const float* __restrict__ in,
                                              const float* __restrict__ W,
                                              float* __restrict__ Hout) {
    int lane = threadIdx.x & 63;
    int wv   = threadIdx.x >> 6;
    int base = blockIdx.x * 32 + wv * 8;           // grid exact (3125*32)
    float xr[8], acc[8];
    #pragma unroll
    for (int r = 0; r < 8; r++) {
        xr[r]  = in[(size_t)(base + r) * 64 + lane];
        acc[r] = 0.f;
    }
    for (int kb = 0; kb < 64; kb += 8) {
        float wb[8];
        #pragma unroll
        for (int j = 0; j < 8; j++) wb[j] = W[(kb + j) * 64 + lane];
        #pragma unroll
        for (int j = 0; j < 8; j++) {
            #pragma unroll
            for (int r = 0; r < 8; r++)
                acc[r] = fmaf(rl_f(xr[r], kb + j), wb[j], acc[r]);
        }
    }
    #pragma unroll
    for (int r = 0; r < 8; r++)
        Hout[(size_t)(base + r) * 64 + lane] = acc[r];
}

// ---------------- Aggregation, 8 nodes per wave ----------------
// A[n] = b + H[n]*dinv2[n] + dinv[n] * sum_j dinv[src_j] * H[src_j]
// MODE 1: Out[n] = relu(A[n]) @ Wn  (one GEMV epilogue for 8 nodes,
//         W rows amortized, 8 independent chains)
// MODE 2: atomicAdd A[n] into pool[batch[n]][lane]  (no A write at all)
template<int MODE>
__global__ __launch_bounds__(256) void k_aggf(const float* __restrict__ Hbuf,
                                              const int2* __restrict__ range,
                                              const int* __restrict__ csr,
                                              const float* __restrict__ dinv,
                                              const float* __restrict__ dinv2,
                                              const float* __restrict__ bias,
                                              const float* __restrict__ Wn,
                                              const int* __restrict__ batch,
                                              float* __restrict__ Out,
                                              float* __restrict__ pool) {
    int wv   = threadIdx.x >> 6;
    int lane = threadIdx.x & 63;
    int n0   = (blockIdx.x * 4 + wv) * 8;          // grid exact (3125*32)

    float b = bias[lane];
    int2  rg[8];
    float hs[8];
    #pragma unroll
    for (int r = 0; r < 8; r++) rg[r] = range[n0 + r];
    #pragma unroll
    for (int r = 0; r < 8; r++) hs[r] = Hbuf[(size_t)(n0 + r) * 64 + lane];

    float A[8];
    #pragma unroll
    for (int r = 0; r < 8; r++) {
        int node = n0 + r;
        int beg = rg[r].x, end = rg[r].y;
        float a0 = 0.f, a1 = 0.f, a2 = 0.f, a3 = 0.f;
        for (int cb = beg; cb < end; cb += 64) {
            int rem = end - cb; if (rem > 64) rem = 64;
            int ci = 0;
            if (lane < rem) ci = csr[cb + lane];
            float cs = dinv[ci];                   // per-lane 4B gather, L2-hot table
            int j = 0;
            for (; j + 8 <= rem; j += 8) {
                int   s0 = rl_i(ci, j),     s1 = rl_i(ci, j + 1);
                int   s2 = rl_i(ci, j + 2), s3 = rl_i(ci, j + 3);
                int   s4 = rl_i(ci, j + 4), s5 = rl_i(ci, j + 5);
                int   s6 = rl_i(ci, j + 6), s7 = rl_i(ci, j + 7);
                float c0 = rl_f(cs, j),     c1 = rl_f(cs, j + 1);
                float c2 = rl_f(cs, j + 2), c3 = rl_f(cs, j + 3);
                float c4 = rl_f(cs, j + 4), c5 = rl_f(cs, j + 5);
                float c6 = rl_f(cs, j + 6), c7 = rl_f(cs, j + 7);
                float h0 = Hbuf[(size_t)s0 * 64 + lane];
                float h1 = Hbuf[(size_t)s1 * 64 + lane];
                float h2 = Hbuf[(size_t)s2 * 64 + lane];
                float h3 = Hbuf[(size_t)s3 * 64 + lane];
                float h4 = Hbuf[(size_t)s4 * 64 + lane];
                float h5 = Hbuf[(size_t)s5 * 64 + lane];
                float h6 = Hbuf[(size_t)s6 * 64 + lane];
                float h7 = Hbuf[(size_t)s7 * 64 + lane];
                a0 = fmaf(h0, c0, a0);
                a1 = fmaf(h1, c1, a1);
                a2 = fmaf(h2, c2, a2);
                a3 = fmaf(h3, c3, a3);
                a0 = fmaf(h4, c4, a0);
                a1 = fmaf(h5, c5, a1);
                a2 = fmaf(h6, c6, a2);
                a3 = fmaf(h7, c7, a3);
            }
            for (; j + 2 <= rem; j += 2) {
                int   s0 = rl_i(ci, j),     s1 = rl_i(ci, j + 1);
                float c0 = rl_f(cs, j),     c1 = rl_f(cs, j + 1);
                float h0 = Hbuf[(size_t)s0 * 64 + lane];
                float h1 = Hbuf[(size_t)s1 * 64 + lane];
                a0 = fmaf(h0, c0, a0);
                a1 = fmaf(h1, c1, a1);
            }
            if (j < rem) {
                int   s0 = rl_i(ci, j);
                float c0 = rl_f(cs, j);
                a0 = fmaf(Hbuf[(size_t)s0 * 64 + lane], c0, a0);
            }
        }
        float esum = (a0 + a1) + (a2 + a3);
        A[r] = fmaf(dinv[node], esum, fmaf(hs[r], dinv2[node], b));
    }

    if (MODE == 1) {
        #pragma unroll
        for (int r = 0; r < 8; r++) A[r] = fmaxf(A[r], 0.f);   // relu
        float o[8];
        #pragma unroll
        for (int r = 0; r < 8; r++) o[r] = 0.f;
        for (int kb = 0; kb < 64; kb += 8) {
            float wb[8];
            #pragma unroll
            for (int j = 0; j < 8; j++) wb[j] = Wn[(kb + j) * 64 + lane];
            #pragma unroll
            for (int j = 0; j < 8; j++) {
                #pragma unroll
                for (int r = 0; r < 8; r++)
                    o[r] = fmaf(rl_f(A[r], kb + j), wb[j], o[r]);
            }
        }
        #pragma unroll
        for (int r = 0; r < 8; r++)
            Out[(size_t)(n0 + r) * 64 + lane] = o[r];          // = H_next
    } else {
        #pragma unroll
        for (int r = 0; r < 8; r++) {
            int g = batch[n0 + r];                             // uniform load
            atomicAdd(&pool[g * 64 + lane], A[r]);
        }
    }
}

// ---------------- mean + classifier ----------------
__device__ __forceinline__ int lbound(const int* __restrict__ a, int n, int v) {
    int lo = 0, hi = n;
    while (lo < hi) { int m = (lo + hi) >> 1; if (a[m] < v) lo = m + 1; else hi = m; }
    return lo;
}

__global__ __launch_bounds__(64) void k_cls(const float* __restrict__ pool, const int* __restrict__ batch,
                                            const float* __restrict__ Wl, const float* __restrict__ bl,
                                            float* __restrict__ out) {
    __shared__ float pm[64];
    __shared__ int bounds[2];
    int g = blockIdx.x;
    int t = threadIdx.x;
    if (t < 2) bounds[t] = lbound(batch, N_NODES, g + t);
    __syncthreads();
    float cnt = (float)(bounds[1] - bounds[0]);
    pm[t] = pool[g * 64 + t] / fmaxf(cnt, 1.0f);
    __syncthreads();
    if (t < N_CLASSES) {
        float o = bl[t];
        #pragma unroll
        for (int k = 0; k < HID; k++) o = fmaf(pm[k], Wl[k * N_CLASSES + t], o);
        out[g * N_CLASSES + t] = o;
    }
}

// ---------------- launch ----------------

extern "C" void kernel_launch(void* const* d_in, const int* in_sizes, int n_in,
                              void* d_out, int out_size, void* d_ws, size_t ws_size,
                              hipStream_t stream) {
    const float* x     = (const float*)d_in[0];
    const int*   eidx  = (const int*)  d_in[1];
    const int*   batch = (const int*)  d_in[2];
    const float* W1 = (const float*)d_in[3];
    const float* b1 = (const float*)d_in[4];
    const float* W2 = (const float*)d_in[5];
    const float* b2 = (const float*)d_in[6];
    const float* W3 = (const float*)d_in[7];
    const float* b3 = (const float*)d_in[8];
    const float* Wl = (const float*)d_in[9];
    const float* bl = (const float*)d_in[10];
    const int* src = eidx;
    const int* dst = eidx + N_EDGES;

    char* p = (char*)d_ws;
    auto alloc = [&](size_t bytes) -> void* {
        void* r = (void*)p;
        p += (bytes + 255) & ~(size_t)255;
        return r;
    };
    int2*  range = (int2*) alloc((size_t)N_NODES * 8);
    float* dinv  = (float*)alloc((size_t)N_NODES * 4);
    float* dinv2 = (float*)alloc((size_t)N_NODES * 4);
    int*   csr   = (int*)  alloc((size_t)SB * CAP * 4);
    float* Hb    = (float*)alloc((size_t)N_NODES * 64 * 4);
    float* Bb    = (float*)alloc((size_t)N_NODES * 64 * 4);
    float* pool  = (float*)alloc((size_t)N_GRAPHS * 64 * 4);
    int*   bcur  = (int*)  alloc((size_t)SB * 4);
    int*   binned = (int*)Hb;   // 7.0 MB scratch aliased onto Hb (dead after k_bcsr)

    const int gemm_grid = N_NODES / 32;            // 3125, exact
    const int agg_grid  = N_NODES / 32;            // 3125 blocks * 4 waves * 8 nodes

    // ---- CSR build ----
    hipMemsetAsync(bcur, 0, (size_t)SB * 4, stream);
    hipMemsetAsync(pool, 0, (size_t)N_GRAPHS * 64 * 4, stream);
    k_scatter<<<NCHUNK, 256, 0, stream>>>(src, dst, bcur, binned);
    k_bcsr   <<<SB, 256, 0, stream>>>(binned, bcur, range, dinv, dinv2, csr);

    // layer 1 GEMM: x -> H1
    k_gemm<<<gemm_grid, 256, 0, stream>>>(x, W1, Hb);
    // agg1 + relu + W2: H1 -> H2
    k_aggf<1><<<agg_grid, 256, 0, stream>>>(Hb, range, csr, dinv, dinv2, b1, W2, batch, Bb, nullptr);
    // agg2 + relu + W3: H2 -> H3
    k_aggf<1><<<agg_grid, 256, 0, stream>>>(Bb, range, csr, dinv, dinv2, b2, W3, batch, Hb, nullptr);
    // agg3 + pooling atomics: H3 -> pool
    k_aggf<2><<<agg_grid, 256, 0, stream>>>(Hb, range, csr, dinv, dinv2, b3, nullptr, batch, nullptr, pool);

    // mean + classifier
    k_cls<<<N_GRAPHS, 64, 0, stream>>>(pool, batch, Wl, bl, (float*)d_out);
}